// Round 1
// baseline (303.517 us; speedup 1.0000x reference)
//
#include <hip/hip_runtime.h>

#define NR 8192      // rows of x and y
#define DK 256       // feature dim (K)
#define BM 128
#define BN 128
#define BK 64

typedef __bf16 bf16x8 __attribute__((ext_vector_type(8)));
typedef float f32x4 __attribute__((ext_vector_type(4)));
typedef unsigned short ushort_t;
typedef unsigned int uint_t;

__device__ __forceinline__ ushort_t f2bf(float f) {
  uint_t u = __float_as_uint(f);
  u += 0x7fffu + ((u >> 16) & 1u);   // round-to-nearest-even
  return (ushort_t)(u >> 16);
}

// Convert f32 rows -> bf16 rows in ws, and compute per-row sum of squares.
// One wave per row; 4 rows per 256-thread block. 16384 rows total (x then y).
__global__ __launch_bounds__(256) void prep_kernel(
    const float* __restrict__ x, const float* __restrict__ y,
    ushort_t* __restrict__ xb, ushort_t* __restrict__ yb,
    float* __restrict__ xsq, float* __restrict__ ysq) {
  int row = blockIdx.x * 4 + (threadIdx.x >> 6);
  int lane = threadIdx.x & 63;
  const float* src; ushort_t* dst; float* sq; int r;
  if (row < NR) { src = x; dst = xb; sq = xsq; r = row; }
  else          { src = y; dst = yb; sq = ysq; r = row - NR; }
  float4 v = ((const float4*)(src + (size_t)r * DK))[lane];
  float s = v.x * v.x + v.y * v.y + v.z * v.z + v.w * v.w;
  ushort4 o;
  o.x = f2bf(v.x); o.y = f2bf(v.y); o.z = f2bf(v.z); o.w = f2bf(v.w);
  ((ushort4*)(dst + (size_t)r * DK))[lane] = o;
#pragma unroll
  for (int off = 32; off; off >>= 1) s += __shfl_xor(s, off, 64);
  if (lane == 0) sq[r] = s;
}

// 128x128 tile bf16 MFMA GEMM with fused RBF epilogue.
// 4 waves in 2x2; each wave owns a 64x64 output sub-tile (4x4 frags of 16x16).
__global__ __launch_bounds__(256) void rbf_gemm(
    const ushort_t* __restrict__ xb, const ushort_t* __restrict__ yb,
    const float* __restrict__ xsq, const float* __restrict__ ysq,
    const float* __restrict__ gptr, float* __restrict__ out) {
  __shared__ ushort_t lds[2 * BM * BK];  // A tile [128][64], B tile [128][64] (32 KiB)
  ushort_t* ldsA = lds;
  ushort_t* ldsB = lds + BM * BK;

  const int t = threadIdx.x;
  const int wid = t >> 6, lane = t & 63;
  const int wm = wid >> 1, wn = wid & 1;
  const int tm = blockIdx.x, tn = blockIdx.y;

  f32x4 acc[4][4];
#pragma unroll
  for (int i = 0; i < 4; ++i)
#pragma unroll
    for (int j = 0; j < 4; ++j)
      acc[i][j] = (f32x4){0.f, 0.f, 0.f, 0.f};

  // staging geometry: chunk c = s*256 + t covers LDS bytes [c*16, c*16+16)
  // => tile row = s*32 + (t>>3), bf16 col = (t&7)*8
  const int c_row = t >> 3;
  const int c_col = (t & 7) * 8;

  for (int kt = 0; kt < DK / BK; ++kt) {
    const int k0 = kt * BK;
#pragma unroll
    for (int s = 0; s < 4; ++s) {
      const ushort_t* gA = xb + (size_t)(tm * BM + s * 32 + c_row) * DK + k0 + c_col;
      const ushort_t* gB = yb + (size_t)(tn * BN + s * 32 + c_row) * DK + k0 + c_col;
      char* lA = (char*)ldsA + s * 4096 + wid * 1024;  // wave-uniform base
      char* lB = (char*)ldsB + s * 4096 + wid * 1024;
      __builtin_amdgcn_global_load_lds(
          (const __attribute__((address_space(1))) void*)gA,
          (__attribute__((address_space(3))) void*)lA, 16, 0, 0);
      __builtin_amdgcn_global_load_lds(
          (const __attribute__((address_space(1))) void*)gB,
          (__attribute__((address_space(3))) void*)lB, 16, 0, 0);
    }
    __syncthreads();

    {
      const int fr = lane & 15, fk = lane >> 4;
      bf16x8 af[4][2], bfr[4][2];
#pragma unroll
      for (int i = 0; i < 4; ++i) {
#pragma unroll
        for (int kk = 0; kk < 2; ++kk) {
          const int rowA = wm * 64 + i * 16 + fr;
          af[i][kk] = *(const bf16x8*)((const char*)ldsA + rowA * 128 + kk * 64 + fk * 16);
          const int rowB = wn * 64 + i * 16 + fr;
          bfr[i][kk] = *(const bf16x8*)((const char*)ldsB + rowB * 128 + kk * 64 + fk * 16);
        }
      }
#pragma unroll
      for (int i = 0; i < 4; ++i)
#pragma unroll
        for (int j = 0; j < 4; ++j)
#pragma unroll
          for (int kk = 0; kk < 2; ++kk)
            acc[i][j] = __builtin_amdgcn_mfma_f32_16x16x32_bf16(
                af[i][kk], bfr[j][kk], acc[i][j], 0, 0, 0);
    }
    __syncthreads();
  }

  // epilogue: out[n][m] = exp(-gamma * max(xsq[n] + ysq[m] - 2*cross, 0))
  const float gamma = *gptr;
  const int fr = lane & 15, fq = lane >> 4;
  const int rowbase = tm * BM + wm * 64;
  const int colbase = tn * BN + wn * 64;
#pragma unroll
  for (int i = 0; i < 4; ++i) {
    float xs[4];
#pragma unroll
    for (int r = 0; r < 4; ++r)
      xs[r] = xsq[rowbase + i * 16 + fq * 4 + r];
#pragma unroll
    for (int j = 0; j < 4; ++j) {
      const int gcol = colbase + j * 16 + fr;
      const float yv = ysq[gcol];
#pragma unroll
      for (int r = 0; r < 4; ++r) {
        const int grow = rowbase + i * 16 + fq * 4 + r;
        float d = xs[r] + yv - 2.0f * acc[i][j][r];
        d = fmaxf(d, 0.0f);
        out[(size_t)grow * NR + gcol] = __expf(-gamma * d);
      }
    }
  }
}

extern "C" void kernel_launch(void* const* d_in, const int* in_sizes, int n_in,
                              void* d_out, int out_size, void* d_ws, size_t ws_size,
                              hipStream_t stream) {
  const float* x = (const float*)d_in[0];
  const float* y = (const float*)d_in[1];
  const float* gamma = (const float*)d_in[2];
  float* out = (float*)d_out;
  char* ws = (char*)d_ws;
  ushort_t* xb = (ushort_t*)ws;                                    // 4 MiB
  ushort_t* yb = (ushort_t*)(ws + (size_t)NR * DK * 2);            // 4 MiB
  float* xsq = (float*)(ws + (size_t)NR * DK * 4);                 // 32 KiB
  float* ysq = (float*)(ws + (size_t)NR * DK * 4 + (size_t)NR * 4);// 32 KiB

  prep_kernel<<<dim3((2 * NR) / 4), dim3(256), 0, stream>>>(x, y, xb, yb, xsq, ysq);
  rbf_gemm<<<dim3(NR / BM, NR / BN), dim3(256), 0, stream>>>(xb, yb, xsq, ysq, gamma, out);
}

// Round 4
// 294.142 us; speedup vs baseline: 1.0319x; 1.0319x over previous
//
#include <hip/hip_runtime.h>

#define NR 8192      // rows of x and y
#define DK 256       // feature dim (K)
#define BM 128
#define BN 128
#define BK 64

typedef __bf16 bf16x8 __attribute__((ext_vector_type(8)));
typedef float f32x4 __attribute__((ext_vector_type(4)));
typedef unsigned short ushort_t;
typedef unsigned int uint_t;

__device__ __forceinline__ ushort_t f2bf(float f) {
  uint_t u = __float_as_uint(f);
  u += 0x7fffu + ((u >> 16) & 1u);   // round-to-nearest-even
  return (ushort_t)(u >> 16);
}

// Convert f32 rows -> bf16 rows in ws, and compute per-row sum of squares.
// One wave per row; 4 rows per 256-thread block. 16384 rows total (x then y).
__global__ __launch_bounds__(256) void prep_kernel(
    const float* __restrict__ x, const float* __restrict__ y,
    ushort_t* __restrict__ xb, ushort_t* __restrict__ yb,
    float* __restrict__ xsq, float* __restrict__ ysq) {
  int row = blockIdx.x * 4 + (threadIdx.x >> 6);
  int lane = threadIdx.x & 63;
  const float* src; ushort_t* dst; float* sq; int r;
  if (row < NR) { src = x; dst = xb; sq = xsq; r = row; }
  else          { src = y; dst = yb; sq = ysq; r = row - NR; }
  float4 v = ((const float4*)(src + (size_t)r * DK))[lane];
  float s = v.x * v.x + v.y * v.y + v.z * v.z + v.w * v.w;
  ushort4 o;
  o.x = f2bf(v.x); o.y = f2bf(v.y); o.z = f2bf(v.z); o.w = f2bf(v.w);
  ((ushort4*)(dst + (size_t)r * DK))[lane] = o;
#pragma unroll
  for (int off = 32; off; off >>= 1) s += __shfl_xor(s, off, 64);
  if (lane == 0) sq[r] = s;
}

// 128x128 tile bf16 MFMA GEMM with fused RBF epilogue.
// 4 waves in 2x2; each wave owns a 64x64 output sub-tile (4x4 frags of 16x16).
// LDS tiles are XOR-swizzled (slot ^= row&7 within each 128B row) to kill the
// 16-way ds_read_b128 bank conflict. global_load_lds writes LINEARLY, so the
// swizzle is applied by permuting the per-lane GLOBAL source column (rule:
// both-sides-or-neither).
__global__ __launch_bounds__(256) void rbf_gemm(
    const ushort_t* __restrict__ xb, const ushort_t* __restrict__ yb,
    const float* __restrict__ xsq, const float* __restrict__ ysq,
    const float* __restrict__ gptr, float* __restrict__ out) {
  __shared__ ushort_t lds[2 * BM * BK];  // A tile [128][64], B tile [128][64] (32 KiB)
  ushort_t* ldsA = lds;
  ushort_t* ldsB = lds + BM * BK;

  const int t = threadIdx.x;
  const int wid = t >> 6, lane = t & 63;
  const int wm = wid >> 1, wn = wid & 1;
  const int tm = blockIdx.x, tn = blockIdx.y;

  f32x4 acc[4][4];
#pragma unroll
  for (int i = 0; i < 4; ++i)
#pragma unroll
    for (int j = 0; j < 4; ++j)
      acc[i][j] = (f32x4){0.f, 0.f, 0.f, 0.f};

  // staging geometry: chunk c = s*256 + t covers LDS bytes [c*16, c*16+16)
  // => LDS tile row = s*32 + (t>>3), 16B slot = t&7.
  // Swizzle: LDS slot holds global slot (slot ^ (row&7)); row&7 == (t>>3)&7.
  const int c_row = t >> 3;
  const int c_col = (((t & 7) ^ ((t >> 3) & 7)) * 8);

  for (int kt = 0; kt < DK / BK; ++kt) {
    const int k0 = kt * BK;
#pragma unroll
    for (int s = 0; s < 4; ++s) {
      const ushort_t* gA = xb + (size_t)(tm * BM + s * 32 + c_row) * DK + k0 + c_col;
      const ushort_t* gB = yb + (size_t)(tn * BN + s * 32 + c_row) * DK + k0 + c_col;
      char* lA = (char*)ldsA + s * 4096 + wid * 1024;  // wave-uniform base
      char* lB = (char*)ldsB + s * 4096 + wid * 1024;
      __builtin_amdgcn_global_load_lds(
          (const __attribute__((address_space(1))) void*)gA,
          (__attribute__((address_space(3))) void*)lA, 16, 0, 0);
      __builtin_amdgcn_global_load_lds(
          (const __attribute__((address_space(1))) void*)gB,
          (__attribute__((address_space(3))) void*)lB, 16, 0, 0);
    }
    __syncthreads();

    {
      const int fr = lane & 15, fk = lane >> 4;
      bf16x8 af[4][2], bfr[4][2];
#pragma unroll
      for (int i = 0; i < 4; ++i) {
#pragma unroll
        for (int kk = 0; kk < 2; ++kk) {
          const int rowA = wm * 64 + i * 16 + fr;
          const int slotA = (kk * 4 + fk) ^ (rowA & 7);
          af[i][kk] = *(const bf16x8*)((const char*)ldsA + rowA * 128 + slotA * 16);
          const int rowB = wn * 64 + i * 16 + fr;
          const int slotB = (kk * 4 + fk) ^ (rowB & 7);
          bfr[i][kk] = *(const bf16x8*)((const char*)ldsB + rowB * 128 + slotB * 16);
        }
      }
#pragma unroll
      for (int i = 0; i < 4; ++i)
#pragma unroll
        for (int j = 0; j < 4; ++j)
#pragma unroll
          for (int kk = 0; kk < 2; ++kk)
            acc[i][j] = __builtin_amdgcn_mfma_f32_16x16x32_bf16(
                af[i][kk], bfr[j][kk], acc[i][j], 0, 0, 0);
    }
    __syncthreads();
  }

  // epilogue: out[n][m] = exp(-gamma * max(xsq[n] + ysq[m] - 2*cross, 0))
  const float gamma = *gptr;
  const int fr = lane & 15, fq = lane >> 4;
  const int rowbase = tm * BM + wm * 64;
  const int colbase = tn * BN + wn * 64;
#pragma unroll
  for (int i = 0; i < 4; ++i) {
    float xs[4];
#pragma unroll
    for (int r = 0; r < 4; ++r)
      xs[r] = xsq[rowbase + i * 16 + fq * 4 + r];
#pragma unroll
    for (int j = 0; j < 4; ++j) {
      const int gcol = colbase + j * 16 + fr;
      const float yv = ysq[gcol];
#pragma unroll
      for (int r = 0; r < 4; ++r) {
        const int grow = rowbase + i * 16 + fq * 4 + r;
        float d = xs[r] + yv - 2.0f * acc[i][j][r];
        d = fmaxf(d, 0.0f);
        out[(size_t)grow * NR + gcol] = __expf(-gamma * d);
      }
    }
  }
}

extern "C" void kernel_launch(void* const* d_in, const int* in_sizes, int n_in,
                              void* d_out, int out_size, void* d_ws, size_t ws_size,
                              hipStream_t stream) {
  const float* x = (const float*)d_in[0];
  const float* y = (const float*)d_in[1];
  const float* gamma = (const float*)d_in[2];
  float* out = (float*)d_out;
  char* ws = (char*)d_ws;
  ushort_t* xb = (ushort_t*)ws;                                    // 4 MiB
  ushort_t* yb = (ushort_t*)(ws + (size_t)NR * DK * 2);            // 4 MiB
  float* xsq = (float*)(ws + (size_t)NR * DK * 4);                 // 32 KiB
  float* ysq = (float*)(ws + (size_t)NR * DK * 4 + (size_t)NR * 4);// 32 KiB

  prep_kernel<<<dim3((2 * NR) / 4), dim3(256), 0, stream>>>(x, y, xb, yb, xsq, ysq);
  rbf_gemm<<<dim3(NR / BM, NR / BN), dim3(256), 0, stream>>>(xb, yb, xsq, ysq, gamma, out);
}